// Round 2
// baseline (3019.514 us; speedup 1.0000x reference)
//
#include <hip/hip_runtime.h>

#define NT 64
#define NH 12
#define HD 32
#define DIM 384
#define NWIN 4096
#define TPB 512
#define PTPB 256

typedef __bf16 bf16;
typedef __bf16 bf16x8 __attribute__((ext_vector_type(8)));
typedef float floatx4 __attribute__((ext_vector_type(4)));

// bf16 weights + fully-expanded rel-pos bias (rewritten every launch; idempotent).
__device__ __align__(16) bf16 g_wqkv[3 * DIM * DIM];   // [1152][384] row = out-channel
__device__ __align__(16) bf16 g_wproj[DIM * DIM];      // [384][384]  row = out-channel
__device__ __align__(16) float g_biasF[NH * NT * NT];  // [12][64][64] bias[h][q][kv]

__global__ void convert_weights(const float* __restrict__ qkv_w,
                                const float* __restrict__ proj_w,
                                const float* __restrict__ bias_table) {
    int i = blockIdx.x * blockDim.x + threadIdx.x;
    if (i < 3 * DIM * DIM) g_wqkv[i] = (bf16)qkv_w[i];
    if (i < DIM * DIM)     g_wproj[i] = (bf16)proj_w[i];
    if (i < NH * NT * NT) {
        int h = i >> 12, qk = i & 4095;
        int q = qk >> 6, kv = qk & 63;
        int idx = ((q >> 3) - (kv >> 3) + 7) * 15 + ((q & 7) - (kv & 7) + 7);
        g_biasF[i] = bias_table[idx * NH + h];
    }
}

// x/A-operand tile in LDS: row stride 768 B, byte-XOR swizzle ((row&7)<<4).
// Per 8-lane phase of a b128 read (rows r..r+7, same col), rows land in 8
// distinct 16B slots -> conflict-free.
__device__ inline bf16x8 sx_ld(const char* base, int row, int colE) {
    return *(const bf16x8*)(base + row * 768 + (((colE) * 2) ^ ((row & 7) << 4)));
}
__device__ inline void sx_st(char* base, int row, int colE, bf16x8 v) {
    *(bf16x8*)(base + row * 768 + (((colE) * 2) ^ ((row & 7) << 4))) = v;
}

// One block per window, 8 waves.
// LDS (77,824 B, 2 blocks/CU):
//   sx  [64]x768B swizzled   @ 0      49,152   (x, bf16, persistent)
//   sq  [2][64][40] bf16     @ 49152  10,240   (pad-40: conflict-free reads)
//   sk  [2][64][40] bf16     @ 59392  10,240
//   svT [2][32][64] bf16     @ 69632   8,192   (col ^= (row&7)<<3)
//   sP  [8][16][64] bf16     @ 49152  16,384   overlay on dead sq/sk (B2 guards)
// Per head-pair: QKV (B-prefetched, 2-m-tile jobs) -> B1 -> scores+softmax in
// regs -> B2 -> sP write + PV -> B3.
__global__ __launch_bounds__(TPB, 4) void attn_kernel(
    const float* __restrict__ x,          // [4096, 64, 384]
    const float* __restrict__ qkv_b,      // [1152]
    float* __restrict__ out)              // [4096, 64, 384] pre-proj attn out
{
    __shared__ __align__(16) char smem[77824];
    bf16 (*sq)[64][40] = (bf16(*)[64][40])(smem + 49152);
    bf16 (*sk)[64][40] = (bf16(*)[64][40])(smem + 59392);
    bf16* svT = (bf16*)(smem + 69632);
    bf16* sP  = (bf16*)(smem + 49152);

    const int t    = threadIdx.x;
    const int win  = blockIdx.x;
    const int wave = t >> 6;
    const int lane = t & 63;
    const int quad = lane >> 4;
    const int l15  = lane & 15;
    const int mt   = wave & 3;   // q-tile for the attention section
    const int grp  = wave >> 2;  // head-in-pair for the attention section

    // ---- stage x -> swizzled bf16 LDS (coalesced: 32 B/thread/iter) ----
    {
        const float4* src = (const float4*)(x + (size_t)win * (NT * DIM));
        #pragma unroll
        for (int it = 0; it < (NT * DIM / 8) / TPB; ++it) {
            int i = t + it * TPB;          // 8-elem chunk id, 0..3071
            float4 f0 = src[i * 2];
            float4 f1 = src[i * 2 + 1];
            int r = i / 48, c8 = (i % 48) * 8;
            bf16x8 v8;
            v8[0] = (bf16)f0.x; v8[1] = (bf16)f0.y; v8[2] = (bf16)f0.z; v8[3] = (bf16)f0.w;
            v8[4] = (bf16)f1.x; v8[5] = (bf16)f1.y; v8[6] = (bf16)f1.z; v8[7] = (bf16)f1.w;
            sx_st(smem, r, c8, v8);
        }
    }
    __syncthreads();

    const float scale = 0.17677669529663687f;  // 32^-0.5
    float* outw = out + (size_t)win * (NT * DIM);
    bf16* const sPw = sP + wave * 1024;

    #pragma unroll 1
    for (int hp = 0; hp < NH / 2; ++hp) {
        // ---- QKV GEMM: jobs = (nt 0..11, m-half 0..1), ids = wave + 8j ----
        // Each B-set (12 frags, 48 VGPR) covers 2 m-tiles = 24 MFMAs.
        // bA/bB two-deep prefetch: job j+1 loads issue before job j compute.
        bf16x8 bA[12], bB[12];

        auto loadB = [&](bf16x8* b, int id) {
            int nt = id >> 1;
            int hl = nt / 6, nt6 = nt % 6;
            int s = nt6 >> 1, nhh = (nt6 & 1) * 16;
            int wrow = s * DIM + (hp * 2 + hl) * HD + nhh + l15;
            const bf16* Wp = g_wqkv + (size_t)wrow * DIM + quad * 8;
            #pragma unroll
            for (int ks = 0; ks < 12; ++ks) b[ks] = *(const bf16x8*)(Wp + ks * 32);
        };
        auto computeStore = [&](const bf16x8* b, int id) {
            int nt = id >> 1, mh = id & 1;
            int hl = nt / 6, nt6 = nt % 6;
            int s = nt6 >> 1, nhh = (nt6 & 1) * 16;
            int wrow = s * DIM + (hp * 2 + hl) * HD + nhh + l15;
            float bv = qkv_b[wrow];
            floatx4 acc0 = {0.f, 0.f, 0.f, 0.f}, acc1 = {0.f, 0.f, 0.f, 0.f};
            #pragma unroll
            for (int ks = 0; ks < 12; ++ks) {
                bf16x8 a0 = sx_ld(smem, mh * 32 + l15,      ks * 32 + quad * 8);
                bf16x8 a1 = sx_ld(smem, mh * 32 + 16 + l15, ks * 32 + quad * 8);
                acc0 = __builtin_amdgcn_mfma_f32_16x16x32_bf16(a0, b[ks], acc0, 0, 0, 0);
                acc1 = __builtin_amdgcn_mfma_f32_16x16x32_bf16(a1, b[ks], acc1, 0, 0, 0);
            }
            #pragma unroll
            for (int im = 0; im < 2; ++im) {
                const floatx4& acc = im ? acc1 : acc0;
                #pragma unroll
                for (int r = 0; r < 4; ++r) {
                    int m = mh * 32 + im * 16 + quad * 4 + r;
                    float v = acc[r] + bv;
                    if (s == 0)      sq[hl][m][nhh + l15] = (bf16)(v * scale);
                    else if (s == 1) sk[hl][m][nhh + l15] = (bf16)v;
                    else {
                        int row = nhh + l15;   // d-channel 0..31
                        svT[hl * 2048 + row * 64 + (m ^ ((row & 7) << 3))] = (bf16)v;
                    }
                }
            }
        };

        loadB(bA, wave);
        loadB(bB, wave + 8);
        computeStore(bA, wave);
        loadB(bA, wave + 16);
        computeStore(bB, wave + 8);
        computeStore(bA, wave + 16);
        __syncthreads();   // B1: q/k/vT visible

        // ---- per-wave attention: wave -> (head grp, q-rows mt*16..+16) ----
        const int h = hp * 2 + grp;
        const float* bias = g_biasF + h * (NT * NT) + (mt * 16 + quad * 4) * NT + l15;
        float bb[4][4];
        #pragma unroll
        for (int jt = 0; jt < 4; ++jt)
            #pragma unroll
            for (int r = 0; r < 4; ++r)
                bb[jt][r] = bias[r * NT + jt * 16];

        const bf16x8 aq = *(const bf16x8*)&sq[grp][mt * 16 + l15][quad * 8];
        floatx4 sc[4];
        #pragma unroll
        for (int jt = 0; jt < 4; ++jt) {
            const bf16x8 bk = *(const bf16x8*)&sk[grp][jt * 16 + l15][quad * 8];
            floatx4 z = {0.f, 0.f, 0.f, 0.f};
            sc[jt] = __builtin_amdgcn_mfma_f32_16x16x32_bf16(aq, bk, z, 0, 0, 0);
        }
        #pragma unroll
        for (int jt = 0; jt < 4; ++jt)
            #pragma unroll
            for (int r = 0; r < 4; ++r)
                sc[jt][r] += bb[jt][r];

        // softmax in-register: row = (quad,r); cols across l15 lanes x 4 jt.
        float mx[4], sm[4], inv[4];
        #pragma unroll
        for (int r = 0; r < 4; ++r) {
            mx[r] = fmaxf(fmaxf(sc[0][r], sc[1][r]), fmaxf(sc[2][r], sc[3][r]));
            mx[r] = fmaxf(mx[r], __shfl_xor(mx[r], 1));
            mx[r] = fmaxf(mx[r], __shfl_xor(mx[r], 2));
            mx[r] = fmaxf(mx[r], __shfl_xor(mx[r], 4));
            mx[r] = fmaxf(mx[r], __shfl_xor(mx[r], 8));
        }
        float e[4][4];
        #pragma unroll
        for (int jt = 0; jt < 4; ++jt)
            #pragma unroll
            for (int r = 0; r < 4; ++r)
                e[jt][r] = __expf(sc[jt][r] - mx[r]);
        #pragma unroll
        for (int r = 0; r < 4; ++r) {
            sm[r] = (e[0][r] + e[1][r]) + (e[2][r] + e[3][r]);
            sm[r] += __shfl_xor(sm[r], 1);
            sm[r] += __shfl_xor(sm[r], 2);
            sm[r] += __shfl_xor(sm[r], 4);
            sm[r] += __shfl_xor(sm[r], 8);
            inv[r] = 1.0f / sm[r];
        }
        __syncthreads();   // B2: sq/sk dead -> sP overlay safe

        // P -> wave-private swizzled LDS tile (transpose for the PV A-operand)
        #pragma unroll
        for (int jt = 0; jt < 4; ++jt)
            #pragma unroll
            for (int r = 0; r < 4; ++r) {
                const int row = quad * 4 + r;
                const int col = jt * 16 + l15;
                sPw[row * 64 + (col ^ ((row & 7) << 3))] = (bf16)(e[jt][r] * inv[r]);
            }

        // ---- PV: out 16x32 per wave, K=64 (2 k-steps x 2 n-tiles) ----
        bf16x8 ap[2];
        #pragma unroll
        for (int ks = 0; ks < 2; ++ks)
            ap[ks] = *(const bf16x8*)&sPw[l15 * 64 + ((ks * 32 + quad * 8) ^ ((l15 & 7) << 3))];
        const bf16* vb = svT + grp * 2048;
        #pragma unroll
        for (int pnt = 0; pnt < 2; ++pnt) {
            floatx4 acc = {0.f, 0.f, 0.f, 0.f};
            #pragma unroll
            for (int ks = 0; ks < 2; ++ks) {
                const int vrow = pnt * 16 + l15;
                const bf16x8 bv = *(const bf16x8*)&vb[vrow * 64 + ((ks * 32 + quad * 8) ^ ((vrow & 7) << 3))];
                acc = __builtin_amdgcn_mfma_f32_16x16x32_bf16(ap[ks], bv, acc, 0, 0, 0);
            }
            #pragma unroll
            for (int r = 0; r < 4; ++r)
                outw[(size_t)(mt * 16 + quad * 4 + r) * DIM + h * HD + pnt * 16 + l15] = acc[r];
        }
        __syncthreads();   // B3: svT/sP dead -> next hp's QKV may overwrite
    }
}

// In-place projection: A staged once in swizzled LDS (49 KB -> 3 blocks/CU),
// wave owns 6 n-tiles, each B-set (12 frags) swept over all 4 m-tiles
// (weight fetched once per block), two-deep bA/bB prefetch.
__global__ __launch_bounds__(PTPB, 3) void proj_kernel(
    const float* __restrict__ proj_b,
    float* __restrict__ out)
{
    __shared__ __align__(16) char smem[49152];
    const int t    = threadIdx.x;
    const int wave = t >> 6;
    const int lane = t & 63;
    const int quad = lane >> 4;
    const int l15  = lane & 15;
    float* base = out + (size_t)blockIdx.x * (NT * DIM);

    {
        const float4* src = (const float4*)base;
        #pragma unroll
        for (int it = 0; it < (NT * DIM / 8) / PTPB; ++it) {
            int i = t + it * PTPB;
            float4 f0 = src[i * 2];
            float4 f1 = src[i * 2 + 1];
            int r = i / 48, c8 = (i % 48) * 8;
            bf16x8 v8;
            v8[0] = (bf16)f0.x; v8[1] = (bf16)f0.y; v8[2] = (bf16)f0.z; v8[3] = (bf16)f0.w;
            v8[4] = (bf16)f1.x; v8[5] = (bf16)f1.y; v8[6] = (bf16)f1.z; v8[7] = (bf16)f1.w;
            sx_st(smem, r, c8, v8);
        }
    }
    __syncthreads();   // all in-place reads of `base` done before any write

    bf16x8 bA[12], bB[12];
    auto loadB = [&](bf16x8* b, int nt) {
        const bf16* Wp = g_wproj + (size_t)(nt * 16 + l15) * DIM + quad * 8;
        #pragma unroll
        for (int ks = 0; ks < 12; ++ks) b[ks] = *(const bf16x8*)(Wp + ks * 32);
    };
    auto computeStore = [&](const bf16x8* b, int nt) {
        floatx4 a0 = {0.f,0.f,0.f,0.f}, a1 = {0.f,0.f,0.f,0.f},
                a2 = {0.f,0.f,0.f,0.f}, a3 = {0.f,0.f,0.f,0.f};
        #pragma unroll
        for (int ks = 0; ks < 12; ++ks) {
            bf16x8 f0 = sx_ld(smem, 0  + l15, ks * 32 + quad * 8);
            bf16x8 f1 = sx_ld(smem, 16 + l15, ks * 32 + quad * 8);
            bf16x8 f2 = sx_ld(smem, 32 + l15, ks * 32 + quad * 8);
            bf16x8 f3 = sx_ld(smem, 48 + l15, ks * 32 + quad * 8);
            a0 = __builtin_amdgcn_mfma_f32_16x16x32_bf16(f0, b[ks], a0, 0, 0, 0);
            a1 = __builtin_amdgcn_mfma_f32_16x16x32_bf16(f1, b[ks], a1, 0, 0, 0);
            a2 = __builtin_amdgcn_mfma_f32_16x16x32_bf16(f2, b[ks], a2, 0, 0, 0);
            a3 = __builtin_amdgcn_mfma_f32_16x16x32_bf16(f3, b[ks], a3, 0, 0, 0);
        }
        float pb = proj_b[nt * 16 + l15];
        #pragma unroll
        for (int r = 0; r < 4; ++r) {
            base[(size_t)(0  + quad * 4 + r) * DIM + nt * 16 + l15] = a0[r] + pb;
            base[(size_t)(16 + quad * 4 + r) * DIM + nt * 16 + l15] = a1[r] + pb;
            base[(size_t)(32 + quad * 4 + r) * DIM + nt * 16 + l15] = a2[r] + pb;
            base[(size_t)(48 + quad * 4 + r) * DIM + nt * 16 + l15] = a3[r] + pb;
        }
    };

    const int n0 = wave * 6;
    loadB(bA, n0 + 0);
    loadB(bB, n0 + 1);
    computeStore(bA, n0 + 0); loadB(bA, n0 + 2);
    computeStore(bB, n0 + 1); loadB(bB, n0 + 3);
    computeStore(bA, n0 + 2); loadB(bA, n0 + 4);
    computeStore(bB, n0 + 3); loadB(bB, n0 + 5);
    computeStore(bA, n0 + 4);
    computeStore(bB, n0 + 5);
}

extern "C" void kernel_launch(void* const* d_in, const int* in_sizes, int n_in,
                              void* d_out, int out_size, void* d_ws, size_t ws_size,
                              hipStream_t stream) {
    const float* x          = (const float*)d_in[0];
    const float* qkv_w      = (const float*)d_in[1];
    const float* qkv_b      = (const float*)d_in[2];
    const float* proj_w     = (const float*)d_in[3];
    const float* proj_b     = (const float*)d_in[4];
    const float* bias_table = (const float*)d_in[5];
    float* out = (float*)d_out;

    convert_weights<<<dim3((3 * DIM * DIM + 255) / 256), dim3(256), 0, stream>>>(qkv_w, proj_w, bias_table);
    attn_kernel<<<dim3(NWIN), dim3(TPB), 0, stream>>>(x, qkv_b, out);
    proj_kernel<<<dim3(NWIN), dim3(PTPB), 0, stream>>>(proj_b, out);
}